// Round 8
// baseline (518.749 us; speedup 1.0000x reference)
//
#include <hip/hip_runtime.h>

#define L_N   16384
#define B_N   4
#define M_N   256
#define HID_N 512
#define PI_F  3.14159265358979323846f

typedef short short8 __attribute__((ext_vector_type(8)));
typedef float f32x4 __attribute__((ext_vector_type(4)));

__device__ __forceinline__ ushort f2bf(float f) {
  uint u = __float_as_uint(f);
  uint r = u + 0x7FFF + ((u >> 16) & 1);
  return (ushort)(r >> 16);
}
__device__ __forceinline__ float bf2f(ushort s) {
  return __uint_as_float(((uint)s) << 16);
}
__device__ __forceinline__ void gld_lds16(const void* g, void* s) {
  __builtin_amdgcn_global_load_lds((const __attribute__((address_space(1))) void*)g,
                                   (__attribute__((address_space(3))) void*)s, 16, 0, 0);
}

// ---------- merged weight transpose: fp32 [R][C] -> bf16 [C][R] ----------
__global__ __launch_bounds__(256) void k_wt_all(
    const float* __restrict__ w_query, const float* __restrict__ w_to_q,
    const float* __restrict__ w_to_kv, const float* __restrict__ w_to_out,
    const float* __restrict__ w_band, const float* __restrict__ w_mod,
    const float* __restrict__ w_hv,
    ushort* __restrict__ wq_t, ushort* __restrict__ wtq_t,
    ushort* __restrict__ wkv_t, ushort* __restrict__ wto_t,
    ushort* __restrict__ wb_t, ushort* __restrict__ wm_t, ushort* __restrict__ whv_t) {
  __shared__ float t[32][33];
  int tb = blockIdx.x;
  const float* in; ushort* out; int R, C;
  if (tb < 64)        { in = w_query;  out = wq_t;  R = 128; C = 512; }
  else if (tb < 128)  { tb -= 64;  in = w_to_q;   out = wtq_t; R = 512; C = 128; }
  else if (tb < 256)  { tb -= 128; in = w_to_kv;  out = wkv_t; R = 512; C = 256; }
  else if (tb < 320)  { tb -= 256; in = w_to_out; out = wto_t; R = 128; C = 512; }
  else if (tb < 512)  { tb -= 320; int kk = tb >> 6; tb &= 63;
                        in = w_band + (size_t)kk * 65536; out = wb_t + (size_t)kk * 65536; R = 128; C = 512; }
  else if (tb < 1280) { tb -= 512; int kk = tb >> 8; tb &= 255;
                        in = w_mod + (size_t)kk * 262144; out = wm_t + (size_t)kk * 262144; R = 512; C = 512; }
  else                { tb -= 1280; int kk = tb >> 8; tb &= 255;
                        in = w_hv + (size_t)kk * 262144; out = whv_t + (size_t)kk * 262144; R = 512; C = 512; }
  int nbx = C >> 5;
  int bx = (tb % nbx) * 32, by = (tb / nbx) * 32;
  int tx = threadIdx.x & 31, ty = threadIdx.x >> 5;
#pragma unroll
  for (int j = 0; j < 32; j += 8) t[ty + j][tx] = in[(size_t)(by + ty + j) * C + bx + tx];
  __syncthreads();
#pragma unroll
  for (int j = 0; j < 32; j += 8)
    out[(size_t)(bx + ty + j) * R + by + tx] = f2bf(t[tx][ty + j]);
}

// ---------- fp32 -> bf16 elementwise ----------
__global__ __launch_bounds__(256) void k_cvt(const float* __restrict__ in,
                                             ushort* __restrict__ out, int n4) {
  int i = blockIdx.x * 256 + threadIdx.x;
  if (i >= n4) return;
  float4 v = *(const float4*)&in[(size_t)i * 4];
  ushort* o = &out[(size_t)i * 4];
  o[0] = f2bf(v.x); o[1] = f2bf(v.y); o[2] = f2bf(v.z); o[3] = f2bf(v.w);
}

// ---------- gamma: [4 specs][L][128] bf16 ----------
__global__ __launch_bounds__(256) void k_gamma(const float* __restrict__ x,
                                               ushort* __restrict__ gout) {
  __shared__ float om[16];
  const float lgs[4] = {2.1072099696478683f, 2.1072099696478683f,
                        1.5051499783199058f, 0.9030899869919435f};
  int spec = blockIdx.y;
  float lg = lgs[spec];
  int tid = threadIdx.x;
  if (tid < 16) om[tid] = powf(10.0f, 1.0f + (float)tid * ((lg - 1.0f) * (1.0f / 15.0f)));
  __syncthreads();
  int l0 = blockIdx.x * 16;
  int idx0 = tid * 8;
  int row = idx0 >> 7, f0 = idx0 & 127;
  int c = f0 >> 5;
  float g = x[(size_t)(l0 + row) * 4 + c];
  float base = PI_F * g;
  int w0 = f0 & 31;
  bool is_cos = (w0 >= 16);
  short8 o;
#pragma unroll
  for (int j = 0; j < 8; ++j) {
    int jf = (w0 + j) & 15;
    float arg = base * om[jf];
    float v = is_cos ? __cosf(arg) : __sinf(arg);
    o[j] = (short)f2bf(v);
  }
  *(short8*)&gout[(size_t)spec * L_N * 128 + (size_t)(l0 + row) * 128 + f0] = o;
}

// ---------- t positions ----------
__global__ __launch_bounds__(256) void k_tpos(const float* __restrict__ x,
                                              const int* dD, const int* dH,
                                              const int* dW, const int* dT,
                                              float* __restrict__ tbuf) {
  int l = blockIdx.x * 256 + threadIdx.x;
  float g0 = x[(size_t)l * 4 + 0], g1 = x[(size_t)l * 4 + 1];
  float g2 = x[(size_t)l * 4 + 2], g3 = x[(size_t)l * 4 + 3];
  int Dd = dD[0], Hh = dH[0], Ww = dW[0], Tt = dT[0];
  int zi = (int)(g0 * (float)Dd), yi = (int)(g1 * (float)Hh);
  int xi = (int)(g2 * (float)Ww), ti = (int)(g3 * (float)Tt);
  int idx = ((ti * Dd + zi) * Hh + yi) * Ww + xi;
  tbuf[l] = (float)idx / (float)(Dd * Hh * Ww * Tt);
}

// ---------- generic bf16 MFMA GEMM, 128x128 tile, BK=64, 2-phase double-buffer ----------
// C = [relu](A@Wt^T + bias + add1) [+ add2]; optional fused w_out partials.
// Flattened 1D grid with bijective XCD swizzle; decomp (nbx, nby, nz).
__global__ __launch_bounds__(256, 2) void k_gemm2(
    const ushort* __restrict__ A, long long sA,
    const ushort* __restrict__ Wt,
    const float* __restrict__ bias,
    const ushort* __restrict__ add1,
    const ushort* add2, long long sAdd2,
    ushort* C, long long sC,
    const float* __restrict__ wout,   // [N][3] fp32 slice of w_out, or nullptr
    float* __restrict__ opb,          // partials [4bx][4z][L][3], or nullptr
    int zoff,
    int N, int K, int do_relu,
    int nbx, int nby, int nz) {
  __shared__ __align__(16) ushort S[2][128 * 64 * 2];   // 64 KB: [buf][As|Ws]
  __shared__ float woutL[384];
  int tid = threadIdx.x;
  int lane = tid & 63, wid = tid >> 6;

  // XCD-aware bijective swizzle (m204)
  int nwg = nbx * nby * nz;
  int gid0 = blockIdx.x;
  int q = nwg >> 3, r = nwg & 7;
  int xcd = gid0 & 7, rank = gid0 >> 3;
  int sid = (xcd < r) ? (xcd * (q + 1) + rank) : (r * (q + 1) + (xcd - r) * q + rank);
  int z = sid / (nbx * nby);
  int rem = sid - z * (nbx * nby);
  int n0 = (rem % nbx) * 128, r0 = (rem / nbx) * 128;

  A += (size_t)z * sA;
  C += (size_t)z * sC;
  const ushort* a2p = add2 ? add2 + (size_t)z * sAdd2 : nullptr;
  int wr = wid >> 1, wc = wid & 1;
  int ksm = K >> 6;

  f32x4 acc[4][4];
#pragma unroll
  for (int i = 0; i < 4; ++i)
#pragma unroll
    for (int j = 0; j < 4; ++j) acc[i][j] = (f32x4)0.0f;

  auto stage = [&](int b, int t) {
    ushort* As = S[b];
    ushort* Ws = S[b] + 128 * 64;
#pragma unroll
    for (int j = 0; j < 4; ++j) {
      int sig = j * 256 + tid;
      int rr = sig >> 3, ph = sig & 7, sl = ph ^ (rr & 7);
      gld_lds16(&A[(size_t)(r0 + rr) * K + t * 64 + sl * 8], &As[(size_t)sig * 8]);
      gld_lds16(&Wt[(size_t)(n0 + rr) * K + t * 64 + sl * 8], &Ws[(size_t)sig * 8]);
    }
  };

  stage(0, 0);
  __syncthreads();
  int cur = 0;
  for (int t = 0; t < ksm; ++t) {
    if (t + 1 < ksm) stage(cur ^ 1, t + 1);   // loads in flight under compute
    ushort* As = S[cur];
    ushort* Ws = S[cur] + 128 * 64;
#pragma unroll
    for (int ks = 0; ks < 2; ++ks) {
      short8 af[4], bg[4];
#pragma unroll
      for (int fm = 0; fm < 4; ++fm) {
        int row = wr * 64 + fm * 16 + (lane & 15);
        af[fm] = *(const short8*)&As[row * 64 + (((ks * 4 + (lane >> 4)) ^ (row & 7)) * 8)];
      }
#pragma unroll
      for (int fn = 0; fn < 4; ++fn) {
        int nl = wc * 64 + fn * 16 + (lane & 15);
        bg[fn] = *(const short8*)&Ws[nl * 64 + (((ks * 4 + (lane >> 4)) ^ (nl & 7)) * 8)];
      }
#pragma unroll
      for (int fm = 0; fm < 4; ++fm)
#pragma unroll
        for (int fn = 0; fn < 4; ++fn)
          acc[fm][fn] = __builtin_amdgcn_mfma_f32_16x16x32_bf16(af[fm], bg[fn], acc[fm][fn], 0, 0, 0);
    }
    __syncthreads();   // drains vmcnt (t+1 loads landed during compute) + protects cur reuse
    cur ^= 1;
  }

  // stage w_out slice (128 cols x 3) to LDS
  if (wout && tid < 128) {
    woutL[tid * 3 + 0] = wout[(size_t)(n0 + tid) * 3 + 0];
    woutL[tid * 3 + 1] = wout[(size_t)(n0 + tid) * 3 + 1];
    woutL[tid * 3 + 2] = wout[(size_t)(n0 + tid) * 3 + 2];
  }

  // vectorized epilogue via LDS staging
  float* Ls = (float*)&S[0][0];   // [32][132] f32
  int row = tid >> 3;
  int c0 = (tid & 7) * 16;
#pragma unroll
  for (int fm = 0; fm < 4; ++fm) {
    if (fm) __syncthreads();
#pragma unroll
    for (int fn = 0; fn < 4; ++fn)
#pragma unroll
      for (int reg = 0; reg < 4; ++reg) {
        int lr = wr * 16 + (lane >> 4) * 4 + reg;
        int lc = wc * 64 + fn * 16 + (lane & 15);
        Ls[lr * 132 + lc] = acc[fm][fn][reg];
      }
    __syncthreads();
    int gr = r0 + (row >> 4) * 64 + fm * 16 + (row & 15);
    float so0 = 0.0f, so1 = 0.0f, so2 = 0.0f;
#pragma unroll
    for (int hh = 0; hh < 2; ++hh) {
      int cc = c0 + hh * 8;
      float v[8];
#pragma unroll
      for (int j = 0; j < 8; ++j) v[j] = Ls[row * 132 + cc + j];
      if (bias) {
#pragma unroll
        for (int j = 0; j < 8; ++j) v[j] += bias[n0 + cc + j];
      }
      if (add1) {
        short8 a1 = *(const short8*)&add1[(size_t)gr * N + n0 + cc];
#pragma unroll
        for (int j = 0; j < 8; ++j) v[j] += bf2f((ushort)a1[j]);
      }
      if (do_relu) {
#pragma unroll
        for (int j = 0; j < 8; ++j) v[j] = fmaxf(v[j], 0.0f);
      }
      if (a2p) {
        short8 a2 = *(const short8*)&a2p[(size_t)gr * N + n0 + cc];
#pragma unroll
        for (int j = 0; j < 8; ++j) v[j] += bf2f((ushort)a2[j]);
      }
      if (wout) {
#pragma unroll
        for (int j = 0; j < 8; ++j) {
          so0 = fmaf(v[j], woutL[(cc + j) * 3 + 0], so0);
          so1 = fmaf(v[j], woutL[(cc + j) * 3 + 1], so1);
          so2 = fmaf(v[j], woutL[(cc + j) * 3 + 2], so2);
        }
      }
      short8 ov;
#pragma unroll
      for (int j = 0; j < 8; ++j) ov[j] = (short)f2bf(v[j]);
      *(short8*)&C[(size_t)gr * N + n0 + cc] = ov;
    }
    if (wout) {
      so0 += __shfl_down(so0, 4); so1 += __shfl_down(so1, 4); so2 += __shfl_down(so2, 4);
      so0 += __shfl_down(so0, 2); so1 += __shfl_down(so1, 2); so2 += __shfl_down(so2, 2);
      so0 += __shfl_down(so0, 1); so1 += __shfl_down(so1, 1); so2 += __shfl_down(so2, 1);
      if ((tid & 7) == 0) {
        int bx = n0 >> 7;
        size_t oi = (((size_t)bx * 4 + (zoff + z)) * L_N + gr) * 3;
        opb[oi + 0] = so0; opb[oi + 1] = so1; opb[oi + 2] = so2;
      }
    }
  }
}

// ---------- reduce out partials: out[z][l] = sum over 3 slots x 4 bx + biases ----------
__global__ __launch_bounds__(256) void k_outred(const float* __restrict__ opb,
                                                const float* __restrict__ b_out,
                                                float* __restrict__ out) {
  int i = blockIdx.x * 256 + threadIdx.x;  // z*L + l
  if (i >= B_N * L_N) return;
  float a0 = b_out[0] + b_out[3] + b_out[6];
  float a1 = b_out[1] + b_out[4] + b_out[7];
  float a2 = b_out[2] + b_out[5] + b_out[8];
  const size_t SS = (size_t)4 * B_N * L_N * 3;  // slot stride
#pragma unroll
  for (int slot = 0; slot < 3; ++slot)
#pragma unroll
    for (int bx = 0; bx < 4; ++bx) {
      const float* p = opb + slot * SS + (((size_t)bx * B_N * L_N) + i) * 3;
      a0 += p[0]; a1 += p[1]; a2 += p[2];
    }
  out[(size_t)i * 3 + 0] = a0;
  out[(size_t)i * 3 + 1] = a1;
  out[(size_t)i * 3 + 2] = a2;
}

// ---------- kv rearrange ----------
__global__ __launch_bounds__(256) void k_rearr(const ushort* __restrict__ kvtmp,
                                               ushort* __restrict__ kbuf,
                                               ushort* __restrict__ vtb) {
  int i = blockIdx.x * 256 + threadIdx.x;
  int col = i & 255, row = i >> 8;
  int b = row >> 8, m = row & 255;
  ushort v = kvtmp[i];
  if (col < 128)
    kbuf[((size_t)b * 256 + m) * 128 + col] = v;
  else
    vtb[(size_t)b * 128 * 256 + (size_t)(col - 128) * 256 + m] = v;
}

// ---------- MFMA attention per (b, head) ----------
__global__ __launch_bounds__(256) void k_attn_m(const ushort* __restrict__ qbuf,
                                                const float* __restrict__ tbuf,
                                                const ushort* __restrict__ kbuf,
                                                const ushort* __restrict__ vtb,
                                                ushort* __restrict__ attn) {
  __shared__ __align__(16) ushort Kt[256 * 64];
  __shared__ __align__(16) ushort Vt[64 * 256];
  __shared__ __align__(16) ushort Qs[64 * 64];
  __shared__ __align__(16) ushort Pw[4][16 * 40];
  __shared__ float ts[64];
  int tid = threadIdx.x;
  int lane = tid & 63, wid = tid >> 6;
  int l0 = blockIdx.x * 64;
  int h = blockIdx.y;
  int z = blockIdx.z;
  const ushort* kbuf_b = kbuf + (size_t)z * M_N * 128;
  const ushort* vtb_b = vtb + (size_t)z * 128 * M_N;
  ushort* attn_b = attn + (size_t)z * L_N * 128;
#pragma unroll
  for (int j = 0; j < 8; ++j) {
    int sig = j * 256 + wid * 64 + lane;
    int m = sig >> 3, ph = sig & 7, sl = ph ^ (m & 7);
    gld_lds16(&kbuf_b[(size_t)m * 128 + h * 64 + sl * 8], &Kt[(size_t)(j * 256 + wid * 64) * 8]);
  }
#pragma unroll
  for (int j = 0; j < 8; ++j) {
    int sig = j * 256 + wid * 64 + lane;
    int d = sig >> 5, ph = sig & 31, sl = ph ^ ((d & 7) << 2);
    gld_lds16(&vtb_b[(size_t)(h * 64 + d) * 256 + sl * 8], &Vt[(size_t)(j * 256 + wid * 64) * 8]);
  }
#pragma unroll
  for (int j = 0; j < 2; ++j) {
    int sig = j * 256 + wid * 64 + lane;
    int q = sig >> 3, ph = sig & 7, sl = ph ^ (q & 7);
    gld_lds16(&qbuf[(size_t)(l0 + q) * 128 + h * 64 + sl * 8], &Qs[(size_t)(j * 256 + wid * 64) * 8]);
  }
  if (tid < 64) ts[tid] = tbuf[l0 + tid];
  __syncthreads();

  f32x4 s_acc[16];
#pragma unroll
  for (int fn = 0; fn < 16; ++fn) s_acc[fn] = (f32x4)0.0f;
#pragma unroll
  for (int ks = 0; ks < 2; ++ks) {
    int qrow = wid * 16 + (lane & 15);
    short8 aq = *(const short8*)&Qs[qrow * 64 + (((ks * 4 + (lane >> 4)) ^ (qrow & 7)) * 8)];
#pragma unroll
    for (int fn = 0; fn < 16; ++fn) {
      int m = fn * 16 + (lane & 15);
      short8 bk = *(const short8*)&Kt[m * 64 + (((ks * 4 + (lane >> 4)) ^ (m & 7)) * 8)];
      s_acc[fn] = __builtin_amdgcn_mfma_f32_16x16x32_bf16(aq, bk, s_acc[fn], 0, 0, 0);
    }
  }
  float mx[4] = {-1e30f, -1e30f, -1e30f, -1e30f};
#pragma unroll
  for (int fn = 0; fn < 16; ++fn) {
#pragma unroll
    for (int reg = 0; reg < 4; ++reg) {
      int ql = wid * 16 + (lane >> 4) * 4 + reg;
      int m = fn * 16 + (lane & 15);
      float mp = ((float)m + 0.5f) * (1.0f / 256.0f);
      float d = ts[ql] - mp;
      float v = s_acc[fn][reg] * 0.125f - 10.0f * d * d;
      s_acc[fn][reg] = v;
      mx[reg] = fmaxf(mx[reg], v);
    }
  }
#pragma unroll
  for (int reg = 0; reg < 4; ++reg) {
    mx[reg] = fmaxf(mx[reg], __shfl_xor(mx[reg], 1));
    mx[reg] = fmaxf(mx[reg], __shfl_xor(mx[reg], 2));
    mx[reg] = fmaxf(mx[reg], __shfl_xor(mx[reg], 4));
    mx[reg] = fmaxf(mx[reg], __shfl_xor(mx[reg], 8));
  }
  float sm[4] = {0.0f, 0.0f, 0.0f, 0.0f};
#pragma unroll
  for (int fn = 0; fn < 16; ++fn) {
#pragma unroll
    for (int reg = 0; reg < 4; ++reg) {
      float e = __expf(s_acc[fn][reg] - mx[reg]);
      s_acc[fn][reg] = e;
      sm[reg] += e;
    }
  }
#pragma unroll
  for (int reg = 0; reg < 4; ++reg) {
    sm[reg] += __shfl_xor(sm[reg], 1);
    sm[reg] += __shfl_xor(sm[reg], 2);
    sm[reg] += __shfl_xor(sm[reg], 4);
    sm[reg] += __shfl_xor(sm[reg], 8);
  }
  float inv[4];
#pragma unroll
  for (int reg = 0; reg < 4; ++reg) inv[reg] = 1.0f / sm[reg];

  f32x4 o_acc[4];
#pragma unroll
  for (int fn = 0; fn < 4; ++fn) o_acc[fn] = (f32x4)0.0f;
  for (int kk = 0; kk < 8; ++kk) {
#pragma unroll
    for (int fp = 0; fp < 2; ++fp) {
      int fn = kk * 2 + fp;
#pragma unroll
      for (int reg = 0; reg < 4; ++reg) {
        int ql16 = (lane >> 4) * 4 + reg;
        int mc = fp * 16 + (lane & 15);
        Pw[wid][ql16 * 40 + mc] = f2bf(s_acc[fn][reg] * inv[reg]);
      }
    }
    asm volatile("s_waitcnt lgkmcnt(0)" ::: "memory");
    __builtin_amdgcn_sched_barrier(0);
    short8 pa = *(const short8*)&Pw[wid][(lane & 15) * 40 + (lane >> 4) * 8];
#pragma unroll
    for (int fn = 0; fn < 4; ++fn) {
      int dr = fn * 16 + (lane & 15);
      short8 vb = *(const short8*)&Vt[dr * 256 + (((kk * 4 + (lane >> 4)) ^ ((dr & 7) << 2)) * 8)];
      o_acc[fn] = __builtin_amdgcn_mfma_f32_16x16x32_bf16(pa, vb, o_acc[fn], 0, 0, 0);
    }
    asm volatile("s_waitcnt lgkmcnt(0)" ::: "memory");
    __builtin_amdgcn_sched_barrier(0);
  }
#pragma unroll
  for (int fn = 0; fn < 4; ++fn)
#pragma unroll
    for (int reg = 0; reg < 4; ++reg) {
      int ql = l0 + wid * 16 + (lane >> 4) * 4 + reg;
      attn_b[(size_t)ql * 128 + h * 64 + fn * 16 + (lane & 15)] = f2bf(o_acc[fn][reg]);
    }
}

extern "C" void kernel_launch(void* const* d_in, const int* in_sizes, int n_in,
                              void* d_out, int out_size, void* d_ws, size_t ws_size,
                              hipStream_t stream) {
  const float* x        = (const float*)d_in[0];
  const float* tokens   = (const float*)d_in[1];
  const float* w_query  = (const float*)d_in[2];
  const float* b_query  = (const float*)d_in[3];
  const float* w_to_q   = (const float*)d_in[4];
  const float* w_to_kv  = (const float*)d_in[5];
  const float* w_to_out = (const float*)d_in[6];
  const float* b_to_out = (const float*)d_in[7];
  const float* w_band   = (const float*)d_in[8];
  const float* b_band   = (const float*)d_in[9];
  const float* w_mod    = (const float*)d_in[10];
  const float* b_mod    = (const float*)d_in[11];
  const float* w_hv     = (const float*)d_in[12];
  const float* b_hv     = (const float*)d_in[13];
  const float* w_out    = (const float*)d_in[14];
  const float* b_out    = (const float*)d_in[15];
  const int* Dd = (const int*)d_in[16];
  const int* Hh = (const int*)d_in[17];
  const int* Ww = (const int*)d_in[18];
  const int* Tt = (const int*)d_in[19];
  float* out = (float*)d_out;

  ushort* W = (ushort*)d_ws;
  size_t o = 0;
  auto alloc = [&](size_t n) { ushort* p = W + o; o += n; return p; };
  const size_t big = (size_t)L_N * HID_N;   // 8388608
  const size_t LQ = (size_t)L_N * 128;      // 2097152
  const size_t OPB_U = (size_t)3 * 4 * B_N * L_N * 3 * 2;

  ushort* gamma  = alloc(4 * LQ);
  ushort* qb     = alloc(LQ);
  ushort* attnout= alloc(4 * LQ);
  ushort* tokb   = alloc((size_t)B_N * M_N * HID_N);
  ushort* kbuf   = alloc((size_t)B_N * M_N * 128);
  ushort* vtb    = alloc((size_t)B_N * 128 * M_N);
  ushort* wq_t   = alloc(512 * 128);
  ushort* wtq_t  = alloc(128 * 512);
  ushort* wkv_t  = alloc(256 * 512);
  ushort* wto_t  = alloc(512 * 128);
  ushort* wb_t   = alloc(3 * 512 * 128);
  ushort* wm_t   = alloc(3 * 512 * 512);
  ushort* whv_t  = alloc(2 * 512 * 512);
  float* tbuf    = (float*)alloc(L_N * 2);
  size_t base_u = o;

  // batched: single hband buffer (recomputed per kk) + opb aliased over attnout
  size_t need_batched = (base_u + big + 3 * 4 * big) * sizeof(ushort);
  bool batched = ws_size >= need_batched;

  ushort* hband; float* opb; ushort *modv, *hv, *tmp;
  if (batched) {
    hband = alloc(big);
    modv = alloc(4 * big); hv = alloc(4 * big); tmp = alloc(4 * big);
    opb = (float*)attnout;                    // attnout dead after modv-GEMM
  } else {
    hband = alloc(3 * big);
    opb = (float*)alloc(OPB_U);
    modv = alloc(big); hv = alloc(big); tmp = alloc(big);
  }
  ushort* xq = modv;        // alias: xq dead before modv written
  ushort* kvtmp = attnout;  // alias: consumed before attnout written

  const long long SL = (long long)big;
  const long long SQ = (long long)LQ;
  const size_t SLOT = (size_t)4 * B_N * L_N * 3;  // opb slot stride (floats)

  // ---- prep ----
  k_wt_all<<<dim3(1792), 256, 0, stream>>>(w_query, w_to_q, w_to_kv, w_to_out, w_band, w_mod, w_hv,
                                           wq_t, wtq_t, wkv_t, wto_t, wb_t, wm_t, whv_t);
  k_cvt<<<dim3(512), 256, 0, stream>>>(tokens, tokb, B_N * M_N * HID_N / 4);
  k_gamma<<<dim3(L_N / 16, 4), 256, 0, stream>>>(x, gamma);
  k_tpos<<<dim3(L_N / 256), 256, 0, stream>>>(x, Dd, Hh, Ww, Tt, tbuf);

  // ---- pre-pass ----
  k_gemm2<<<dim3(4 * 128), 256, 0, stream>>>(gamma, 0, wq_t, b_query, nullptr, nullptr, 0,
                                             xq, 0, nullptr, nullptr, 0, 512, 128, 1, 4, 128, 1);
  k_gemm2<<<dim3(1 * 128), 256, 0, stream>>>(xq, 0, wtq_t, nullptr, nullptr, nullptr, 0,
                                             qb, 0, nullptr, nullptr, 0, 128, 512, 0, 1, 128, 1);
  k_gemm2<<<dim3(2 * 8), 256, 0, stream>>>(tokb, 0, wkv_t, nullptr, nullptr, nullptr, 0,
                                           kvtmp, 0, nullptr, nullptr, 0, 256, 512, 0, 2, 8, 1);
  k_rearr<<<dim3(1024), 256, 0, stream>>>(kvtmp, kbuf, vtb);
  k_attn_m<<<dim3(L_N / 64, 2, 4), 256, 0, stream>>>(qb, tbuf, kbuf, vtb, attnout);

  if (batched) {
    k_gemm2<<<dim3(4 * 128 * 4), 256, 0, stream>>>(attnout, SQ, wto_t, b_to_out, nullptr, nullptr, 0,
                                                   modv, SL, nullptr, nullptr, 0, 512, 128, 0, 4, 128, 4);
    for (int kk = 0; kk < 3; ++kk) {
      k_gemm2<<<dim3(4 * 128), 256, 0, stream>>>(gamma + (size_t)(1 + kk) * LQ, 0,
                                                 wb_t + (size_t)kk * 65536, b_band + kk * 512,
                                                 nullptr, nullptr, 0, hband, 0,
                                                 nullptr, nullptr, 0, 512, 128, 1, 4, 128, 1);
      if (kk == 0) {
        k_gemm2<<<dim3(4 * 128 * 4), 256, 0, stream>>>(modv, SL, wm_t, b_mod, hband, nullptr, 0,
                                                       hv, SL, w_out, opb, 0, 512, 512, 1, 4, 128, 4);
      } else {
        k_gemm2<<<dim3(4 * 128 * 4), 256, 0, stream>>>(modv, SL, wm_t + (size_t)kk * 262144,
                                                       b_mod + kk * 512, hband, hv, SL,
                                                       tmp, SL, nullptr, nullptr, 0, 512, 512, 1, 4, 128, 4);
        k_gemm2<<<dim3(4 * 128 * 4), 256, 0, stream>>>(tmp, SL, whv_t + (size_t)(kk - 1) * 262144,
                                                       b_hv + (kk - 1) * 512, nullptr, nullptr, 0,
                                                       hv, SL, w_out + (size_t)kk * 1536,
                                                       opb + (size_t)kk * SLOT, 0, 512, 512, 1, 4, 128, 4);
      }
    }
  } else {
    for (int kk = 0; kk < 3; ++kk)
      k_gemm2<<<dim3(4 * 128), 256, 0, stream>>>(gamma + (size_t)(1 + kk) * LQ, 0,
                                                 wb_t + (size_t)kk * 65536, b_band + kk * 512,
                                                 nullptr, nullptr, 0, hband + (size_t)kk * big, 0,
                                                 nullptr, nullptr, 0, 512, 128, 1, 4, 128, 1);
    for (int z = 0; z < B_N; ++z) {
      k_gemm2<<<dim3(4 * 128), 256, 0, stream>>>(attnout + (size_t)z * LQ, 0, wto_t, b_to_out,
                                                 nullptr, nullptr, 0, modv, 0,
                                                 nullptr, nullptr, 0, 512, 128, 0, 4, 128, 1);
      k_gemm2<<<dim3(4 * 128), 256, 0, stream>>>(modv, 0, wm_t, b_mod, hband, nullptr, 0,
                                                 hv, 0, w_out, opb, z, 512, 512, 1, 4, 128, 1);
      for (int kk = 1; kk < 3; ++kk) {
        k_gemm2<<<dim3(4 * 128), 256, 0, stream>>>(modv, 0, wm_t + (size_t)kk * 262144,
                                                   b_mod + kk * 512, hband + (size_t)kk * big, hv, 0,
                                                   tmp, 0, nullptr, nullptr, 0, 512, 512, 1, 4, 128, 1);
        k_gemm2<<<dim3(4 * 128), 256, 0, stream>>>(tmp, 0, whv_t + (size_t)(kk - 1) * 262144,
                                                   b_hv + (kk - 1) * 512, nullptr, nullptr, 0,
                                                   hv, 0, w_out + (size_t)kk * 1536,
                                                   opb + (size_t)kk * SLOT, z, 512, 512, 1, 4, 128, 1);
      }
    }
  }
  k_outred<<<dim3((B_N * L_N + 255) / 256), 256, 0, stream>>>(opb, b_out, out);
}

// Round 9
// 448.571 us; speedup vs baseline: 1.1564x; 1.1564x over previous
//
#include <hip/hip_runtime.h>

#define L_N   16384
#define B_N   4
#define M_N   256
#define HID_N 512
#define PI_F  3.14159265358979323846f

typedef short short8 __attribute__((ext_vector_type(8)));
typedef float f32x4 __attribute__((ext_vector_type(4)));

__device__ __forceinline__ ushort f2bf(float f) {
  uint u = __float_as_uint(f);
  uint r = u + 0x7FFF + ((u >> 16) & 1);
  return (ushort)(r >> 16);
}
__device__ __forceinline__ float bf2f(ushort s) {
  return __uint_as_float(((uint)s) << 16);
}
__device__ __forceinline__ void gld_lds16(const void* g, void* s) {
  __builtin_amdgcn_global_load_lds((const __attribute__((address_space(1))) void*)g,
                                   (__attribute__((address_space(3))) void*)s, 16, 0, 0);
}

// ---------- merged weight transpose: fp32 [R][C] -> bf16 [C][R] ----------
__global__ __launch_bounds__(256) void k_wt_all(
    const float* __restrict__ w_query, const float* __restrict__ w_to_q,
    const float* __restrict__ w_to_kv, const float* __restrict__ w_to_out,
    const float* __restrict__ w_band, const float* __restrict__ w_mod,
    const float* __restrict__ w_hv,
    ushort* __restrict__ wq_t, ushort* __restrict__ wtq_t,
    ushort* __restrict__ wkv_t, ushort* __restrict__ wto_t,
    ushort* __restrict__ wb_t, ushort* __restrict__ wm_t, ushort* __restrict__ whv_t) {
  __shared__ float t[32][33];
  int tb = blockIdx.x;
  const float* in; ushort* out; int R, C;
  if (tb < 64)        { in = w_query;  out = wq_t;  R = 128; C = 512; }
  else if (tb < 128)  { tb -= 64;  in = w_to_q;   out = wtq_t; R = 512; C = 128; }
  else if (tb < 256)  { tb -= 128; in = w_to_kv;  out = wkv_t; R = 512; C = 256; }
  else if (tb < 320)  { tb -= 256; in = w_to_out; out = wto_t; R = 128; C = 512; }
  else if (tb < 512)  { tb -= 320; int kk = tb >> 6; tb &= 63;
                        in = w_band + (size_t)kk * 65536; out = wb_t + (size_t)kk * 65536; R = 128; C = 512; }
  else if (tb < 1280) { tb -= 512; int kk = tb >> 8; tb &= 255;
                        in = w_mod + (size_t)kk * 262144; out = wm_t + (size_t)kk * 262144; R = 512; C = 512; }
  else                { tb -= 1280; int kk = tb >> 8; tb &= 255;
                        in = w_hv + (size_t)kk * 262144; out = whv_t + (size_t)kk * 262144; R = 512; C = 512; }
  int nbx = C >> 5;
  int bx = (tb % nbx) * 32, by = (tb / nbx) * 32;
  int tx = threadIdx.x & 31, ty = threadIdx.x >> 5;
#pragma unroll
  for (int j = 0; j < 32; j += 8) t[ty + j][tx] = in[(size_t)(by + ty + j) * C + bx + tx];
  __syncthreads();
#pragma unroll
  for (int j = 0; j < 32; j += 8)
    out[(size_t)(bx + ty + j) * R + by + tx] = f2bf(t[tx][ty + j]);
}

// ---------- fp32 -> bf16 elementwise ----------
__global__ __launch_bounds__(256) void k_cvt(const float* __restrict__ in,
                                             ushort* __restrict__ out, int n4) {
  int i = blockIdx.x * 256 + threadIdx.x;
  if (i >= n4) return;
  float4 v = *(const float4*)&in[(size_t)i * 4];
  ushort* o = &out[(size_t)i * 4];
  o[0] = f2bf(v.x); o[1] = f2bf(v.y); o[2] = f2bf(v.z); o[3] = f2bf(v.w);
}

// ---------- gamma: [4 specs][L][128] bf16 ----------
__global__ __launch_bounds__(256) void k_gamma(const float* __restrict__ x,
                                               ushort* __restrict__ gout) {
  __shared__ float om[16];
  const float lgs[4] = {2.1072099696478683f, 2.1072099696478683f,
                        1.5051499783199058f, 0.9030899869919435f};
  int spec = blockIdx.y;
  float lg = lgs[spec];
  int tid = threadIdx.x;
  if (tid < 16) om[tid] = powf(10.0f, 1.0f + (float)tid * ((lg - 1.0f) * (1.0f / 15.0f)));
  __syncthreads();
  int l0 = blockIdx.x * 16;
  int idx0 = tid * 8;
  int row = idx0 >> 7, f0 = idx0 & 127;
  int c = f0 >> 5;
  float g = x[(size_t)(l0 + row) * 4 + c];
  float base = PI_F * g;
  int w0 = f0 & 31;
  bool is_cos = (w0 >= 16);
  short8 o;
#pragma unroll
  for (int j = 0; j < 8; ++j) {
    int jf = (w0 + j) & 15;
    float arg = base * om[jf];
    float v = is_cos ? __cosf(arg) : __sinf(arg);
    o[j] = (short)f2bf(v);
  }
  *(short8*)&gout[(size_t)spec * L_N * 128 + (size_t)(l0 + row) * 128 + f0] = o;
}

// ---------- t positions ----------
__global__ __launch_bounds__(256) void k_tpos(const float* __restrict__ x,
                                              const int* dD, const int* dH,
                                              const int* dW, const int* dT,
                                              float* __restrict__ tbuf) {
  int l = blockIdx.x * 256 + threadIdx.x;
  float g0 = x[(size_t)l * 4 + 0], g1 = x[(size_t)l * 4 + 1];
  float g2 = x[(size_t)l * 4 + 2], g3 = x[(size_t)l * 4 + 3];
  int Dd = dD[0], Hh = dH[0], Ww = dW[0], Tt = dT[0];
  int zi = (int)(g0 * (float)Dd), yi = (int)(g1 * (float)Hh);
  int xi = (int)(g2 * (float)Ww), ti = (int)(g3 * (float)Tt);
  int idx = ((ti * Dd + zi) * Hh + yi) * Ww + xi;
  tbuf[l] = (float)idx / (float)(Dd * Hh * Ww * Tt);
}

// ---------- generic bf16 MFMA GEMM, 128x128 tile, BK=64, single-buffer LDS ----------
// (R6-proven structure; added z-strides for Wt/bias so batched hband fits one launch)
__global__ __launch_bounds__(256, 4) void k_gemm2(
    const ushort* __restrict__ A, long long sA,
    const ushort* __restrict__ Wt, long long sWt,
    const float* __restrict__ bias, int sBias,
    const ushort* __restrict__ add1,
    const ushort* add2, long long sAdd2,
    ushort* C, long long sC,
    const float* __restrict__ wout,   // [N][3] fp32 slice of w_out, or nullptr
    float* __restrict__ opb,          // partials [4bx][4z][L][3], or nullptr
    int zoff,
    int N, int K, int do_relu,
    int nbx, int nby, int nz) {
  __shared__ __align__(16) ushort S[128 * 64 * 2];   // 32 KB: As | Ws
  __shared__ float woutL[384];
  ushort* As = S;
  ushort* Ws = S + 128 * 64;
  int tid = threadIdx.x;
  int lane = tid & 63, wid = tid >> 6;

  // XCD-aware bijective swizzle (m204)
  int nwg = nbx * nby * nz;
  int gid0 = blockIdx.x;
  int q = nwg >> 3, r = nwg & 7;
  int xcd = gid0 & 7, rank = gid0 >> 3;
  int sid = (xcd < r) ? (xcd * (q + 1) + rank) : (r * (q + 1) + (xcd - r) * q + rank);
  int z = sid / (nbx * nby);
  int rem = sid - z * (nbx * nby);
  int n0 = (rem % nbx) * 128, r0 = (rem / nbx) * 128;

  A += (size_t)z * sA;
  C += (size_t)z * sC;
  const ushort* Wtp = Wt + (size_t)z * sWt;
  const float* biasp = bias ? bias + (size_t)z * sBias : nullptr;
  const ushort* a2p = add2 ? add2 + (size_t)z * sAdd2 : nullptr;
  int wr = wid >> 1, wc = wid & 1;
  int ksm = K >> 6;

  f32x4 acc[4][4];
#pragma unroll
  for (int i = 0; i < 4; ++i)
#pragma unroll
    for (int j = 0; j < 4; ++j) acc[i][j] = (f32x4)0.0f;

  for (int t = 0; t < ksm; ++t) {
#pragma unroll
    for (int j = 0; j < 4; ++j) {
      int sig = j * 256 + wid * 64 + lane;
      int rr = sig >> 3, ph = sig & 7, sl = ph ^ (rr & 7);
      gld_lds16(&A[(size_t)(r0 + rr) * K + t * 64 + sl * 8], &As[(size_t)(j * 256 + wid * 64) * 8]);
      gld_lds16(&Wtp[(size_t)(n0 + rr) * K + t * 64 + sl * 8], &Ws[(size_t)(j * 256 + wid * 64) * 8]);
    }
    __syncthreads();
#pragma unroll
    for (int ks = 0; ks < 2; ++ks) {
      short8 af[4], bg[4];
#pragma unroll
      for (int fm = 0; fm < 4; ++fm) {
        int row = wr * 64 + fm * 16 + (lane & 15);
        af[fm] = *(const short8*)&As[row * 64 + (((ks * 4 + (lane >> 4)) ^ (row & 7)) * 8)];
      }
#pragma unroll
      for (int fn = 0; fn < 4; ++fn) {
        int nl = wc * 64 + fn * 16 + (lane & 15);
        bg[fn] = *(const short8*)&Ws[nl * 64 + (((ks * 4 + (lane >> 4)) ^ (nl & 7)) * 8)];
      }
#pragma unroll
      for (int fm = 0; fm < 4; ++fm)
#pragma unroll
        for (int fn = 0; fn < 4; ++fn)
          acc[fm][fn] = __builtin_amdgcn_mfma_f32_16x16x32_bf16(af[fm], bg[fn], acc[fm][fn], 0, 0, 0);
    }
    __syncthreads();
  }

  // stage w_out slice (128 cols x 3) to LDS
  if (wout && tid < 128) {
    woutL[tid * 3 + 0] = wout[(size_t)(n0 + tid) * 3 + 0];
    woutL[tid * 3 + 1] = wout[(size_t)(n0 + tid) * 3 + 1];
    woutL[tid * 3 + 2] = wout[(size_t)(n0 + tid) * 3 + 2];
  }

  // vectorized epilogue via LDS staging
  float* Ls = (float*)S;   // [32][132] f32
  int row = tid >> 3;
  int c0 = (tid & 7) * 16;
#pragma unroll
  for (int fm = 0; fm < 4; ++fm) {
    if (fm) __syncthreads();
#pragma unroll
    for (int fn = 0; fn < 4; ++fn)
#pragma unroll
      for (int reg = 0; reg < 4; ++reg) {
        int lr = wr * 16 + (lane >> 4) * 4 + reg;
        int lc = wc * 64 + fn * 16 + (lane & 15);
        Ls[lr * 132 + lc] = acc[fm][fn][reg];
      }
    __syncthreads();
    int gr = r0 + (row >> 4) * 64 + fm * 16 + (row & 15);
    float so0 = 0.0f, so1 = 0.0f, so2 = 0.0f;
#pragma unroll
    for (int hh = 0; hh < 2; ++hh) {
      int cc = c0 + hh * 8;
      float v[8];
#pragma unroll
      for (int j = 0; j < 8; ++j) v[j] = Ls[row * 132 + cc + j];
      if (biasp) {
#pragma unroll
        for (int j = 0; j < 8; ++j) v[j] += biasp[n0 + cc + j];
      }
      if (add1) {
        short8 a1 = *(const short8*)&add1[(size_t)gr * N + n0 + cc];
#pragma unroll
        for (int j = 0; j < 8; ++j) v[j] += bf2f((ushort)a1[j]);
      }
      if (do_relu) {
#pragma unroll
        for (int j = 0; j < 8; ++j) v[j] = fmaxf(v[j], 0.0f);
      }
      if (a2p) {
        short8 a2 = *(const short8*)&a2p[(size_t)gr * N + n0 + cc];
#pragma unroll
        for (int j = 0; j < 8; ++j) v[j] += bf2f((ushort)a2[j]);
      }
      if (wout) {
#pragma unroll
        for (int j = 0; j < 8; ++j) {
          so0 = fmaf(v[j], woutL[(cc + j) * 3 + 0], so0);
          so1 = fmaf(v[j], woutL[(cc + j) * 3 + 1], so1);
          so2 = fmaf(v[j], woutL[(cc + j) * 3 + 2], so2);
        }
      }
      short8 ov;
#pragma unroll
      for (int j = 0; j < 8; ++j) ov[j] = (short)f2bf(v[j]);
      *(short8*)&C[(size_t)gr * N + n0 + cc] = ov;
    }
    if (wout) {
      so0 += __shfl_down(so0, 4); so1 += __shfl_down(so1, 4); so2 += __shfl_down(so2, 4);
      so0 += __shfl_down(so0, 2); so1 += __shfl_down(so1, 2); so2 += __shfl_down(so2, 2);
      so0 += __shfl_down(so0, 1); so1 += __shfl_down(so1, 1); so2 += __shfl_down(so2, 1);
      if ((tid & 7) == 0) {
        int bx = n0 >> 7;
        size_t oi = (((size_t)bx * 4 + (zoff + z)) * L_N + gr) * 3;
        opb[oi + 0] = so0; opb[oi + 1] = so1; opb[oi + 2] = so2;
      }
    }
  }
}

// ---------- reduce out partials ----------
__global__ __launch_bounds__(256) void k_outred(const float* __restrict__ opb,
                                                const float* __restrict__ b_out,
                                                float* __restrict__ out) {
  int i = blockIdx.x * 256 + threadIdx.x;  // z*L + l
  if (i >= B_N * L_N) return;
  float a0 = b_out[0] + b_out[3] + b_out[6];
  float a1 = b_out[1] + b_out[4] + b_out[7];
  float a2 = b_out[2] + b_out[5] + b_out[8];
  const size_t SS = (size_t)4 * B_N * L_N * 3;
#pragma unroll
  for (int slot = 0; slot < 3; ++slot)
#pragma unroll
    for (int bx = 0; bx < 4; ++bx) {
      const float* p = opb + slot * SS + (((size_t)bx * B_N * L_N) + i) * 3;
      a0 += p[0]; a1 += p[1]; a2 += p[2];
    }
  out[(size_t)i * 3 + 0] = a0;
  out[(size_t)i * 3 + 1] = a1;
  out[(size_t)i * 3 + 2] = a2;
}

// ---------- kv rearrange ----------
__global__ __launch_bounds__(256) void k_rearr(const ushort* __restrict__ kvtmp,
                                               ushort* __restrict__ kbuf,
                                               ushort* __restrict__ vtb) {
  int i = blockIdx.x * 256 + threadIdx.x;
  int col = i & 255, row = i >> 8;
  int b = row >> 8, m = row & 255;
  ushort v = kvtmp[i];
  if (col < 128)
    kbuf[((size_t)b * 256 + m) * 128 + col] = v;
  else
    vtb[(size_t)b * 128 * 256 + (size_t)(col - 128) * 256 + m] = v;
}

// ---------- MFMA attention per (b, head) ----------
__global__ __launch_bounds__(256) void k_attn_m(const ushort* __restrict__ qbuf,
                                                const float* __restrict__ tbuf,
                                                const ushort* __restrict__ kbuf,
                                                const ushort* __restrict__ vtb,
                                                ushort* __restrict__ attn) {
  __shared__ __align__(16) ushort Kt[256 * 64];
  __shared__ __align__(16) ushort Vt[64 * 256];
  __shared__ __align__(16) ushort Qs[64 * 64];
  __shared__ __align__(16) ushort Pw[4][16 * 40];
  __shared__ float ts[64];
  int tid = threadIdx.x;
  int lane = tid & 63, wid = tid >> 6;
  int l0 = blockIdx.x * 64;
  int h = blockIdx.y;
  int z = blockIdx.z;
  const ushort* kbuf_b = kbuf + (size_t)z * M_N * 128;
  const ushort* vtb_b = vtb + (size_t)z * 128 * M_N;
  ushort* attn_b = attn + (size_t)z * L_N * 128;
#pragma unroll
  for (int j = 0; j < 8; ++j) {
    int sig = j * 256 + wid * 64 + lane;
    int m = sig >> 3, ph = sig & 7, sl = ph ^ (m & 7);
    gld_lds16(&kbuf_b[(size_t)m * 128 + h * 64 + sl * 8], &Kt[(size_t)(j * 256 + wid * 64) * 8]);
  }
#pragma unroll
  for (int j = 0; j < 8; ++j) {
    int sig = j * 256 + wid * 64 + lane;
    int d = sig >> 5, ph = sig & 31, sl = ph ^ ((d & 7) << 2);
    gld_lds16(&vtb_b[(size_t)(h * 64 + d) * 256 + sl * 8], &Vt[(size_t)(j * 256 + wid * 64) * 8]);
  }
#pragma unroll
  for (int j = 0; j < 2; ++j) {
    int sig = j * 256 + wid * 64 + lane;
    int q = sig >> 3, ph = sig & 7, sl = ph ^ (q & 7);
    gld_lds16(&qbuf[(size_t)(l0 + q) * 128 + h * 64 + sl * 8], &Qs[(size_t)(j * 256 + wid * 64) * 8]);
  }
  if (tid < 64) ts[tid] = tbuf[l0 + tid];
  __syncthreads();

  f32x4 s_acc[16];
#pragma unroll
  for (int fn = 0; fn < 16; ++fn) s_acc[fn] = (f32x4)0.0f;
#pragma unroll
  for (int ks = 0; ks < 2; ++ks) {
    int qrow = wid * 16 + (lane & 15);
    short8 aq = *(const short8*)&Qs[qrow * 64 + (((ks * 4 + (lane >> 4)) ^ (qrow & 7)) * 8)];
#pragma unroll
    for (int fn = 0; fn < 16; ++fn) {
      int m = fn * 16 + (lane & 15);
      short8 bk = *(const short8*)&Kt[m * 64 + (((ks * 4 + (lane >> 4)) ^ (m & 7)) * 8)];
      s_acc[fn] = __builtin_amdgcn_mfma_f32_16x16x32_bf16(aq, bk, s_acc[fn], 0, 0, 0);
    }
  }
  float mx[4] = {-1e30f, -1e30f, -1e30f, -1e30f};
#pragma unroll
  for (int fn = 0; fn < 16; ++fn) {
#pragma unroll
    for (int reg = 0; reg < 4; ++reg) {
      int ql = wid * 16 + (lane >> 4) * 4 + reg;
      int m = fn * 16 + (lane & 15);
      float mp = ((float)m + 0.5f) * (1.0f / 256.0f);
      float d = ts[ql] - mp;
      float v = s_acc[fn][reg] * 0.125f - 10.0f * d * d;
      s_acc[fn][reg] = v;
      mx[reg] = fmaxf(mx[reg], v);
    }
  }
#pragma unroll
  for (int reg = 0; reg < 4; ++reg) {
    mx[reg] = fmaxf(mx[reg], __shfl_xor(mx[reg], 1));
    mx[reg] = fmaxf(mx[reg], __shfl_xor(mx[reg], 2));
    mx[reg] = fmaxf(mx[reg], __shfl_xor(mx[reg], 4));
    mx[reg] = fmaxf(mx[reg], __shfl_xor(mx[reg], 8));
  }
  float sm[4] = {0.0f, 0.0f, 0.0f, 0.0f};
#pragma unroll
  for (int fn = 0; fn < 16; ++fn) {
#pragma unroll
    for (int reg = 0; reg < 4; ++reg) {
      float e = __expf(s_acc[fn][reg] - mx[reg]);
      s_acc[fn][reg] = e;
      sm[reg] += e;
    }
  }
#pragma unroll
  for (int reg = 0; reg < 4; ++reg) {
    sm[reg] += __shfl_xor(sm[reg], 1);
    sm[reg] += __shfl_xor(sm[reg], 2);
    sm[reg] += __shfl_xor(sm[reg], 4);
    sm[reg] += __shfl_xor(sm[reg], 8);
  }
  float inv[4];
#pragma unroll
  for (int reg = 0; reg < 4; ++reg) inv[reg] = 1.0f / sm[reg];

  f32x4 o_acc[4];
#pragma unroll
  for (int fn = 0; fn < 4; ++fn) o_acc[fn] = (f32x4)0.0f;
  for (int kk = 0; kk < 8; ++kk) {
#pragma unroll
    for (int fp = 0; fp < 2; ++fp) {
      int fn = kk * 2 + fp;
#pragma unroll
      for (int reg = 0; reg < 4; ++reg) {
        int ql16 = (lane >> 4) * 4 + reg;
        int mc = fp * 16 + (lane & 15);
        Pw[wid][ql16 * 40 + mc] = f2bf(s_acc[fn][reg] * inv[reg]);
      }
    }
    asm volatile("s_waitcnt lgkmcnt(0)" ::: "memory");
    __builtin_amdgcn_sched_barrier(0);
    short8 pa = *(const short8*)&Pw[wid][(lane & 15) * 40 + (lane >> 4) * 8];
#pragma unroll
    for (int fn = 0; fn < 4; ++fn) {
      int dr = fn * 16 + (lane & 15);
      short8 vb = *(const short8*)&Vt[dr * 256 + (((kk * 4 + (lane >> 4)) ^ ((dr & 7) << 2)) * 8)];
      o_acc[fn] = __builtin_amdgcn_mfma_f32_16x16x32_bf16(pa, vb, o_acc[fn], 0, 0, 0);
    }
    asm volatile("s_waitcnt lgkmcnt(0)" ::: "memory");
    __builtin_amdgcn_sched_barrier(0);
  }
#pragma unroll
  for (int fn = 0; fn < 4; ++fn)
#pragma unroll
    for (int reg = 0; reg < 4; ++reg) {
      int ql = l0 + wid * 16 + (lane >> 4) * 4 + reg;
      attn_b[(size_t)ql * 128 + h * 64 + fn * 16 + (lane & 15)] = f2bf(o_acc[fn][reg]);
    }
}

extern "C" void kernel_launch(void* const* d_in, const int* in_sizes, int n_in,
                              void* d_out, int out_size, void* d_ws, size_t ws_size,
                              hipStream_t stream) {
  const float* x        = (const float*)d_in[0];
  const float* tokens   = (const float*)d_in[1];
  const float* w_query  = (const float*)d_in[2];
  const float* b_query  = (const float*)d_in[3];
  const float* w_to_q   = (const float*)d_in[4];
  const float* w_to_kv  = (const float*)d_in[5];
  const float* w_to_out = (const float*)d_in[6];
  const float* b_to_out = (const float*)d_in[7];
  const float* w_band   = (const float*)d_in[8];
  const float* b_band   = (const float*)d_in[9];
  const float* w_mod    = (const float*)d_in[10];
  const float* b_mod    = (const float*)d_in[11];
  const float* w_hv     = (const float*)d_in[12];
  const float* b_hv     = (const float*)d_in[13];
  const float* w_out    = (const float*)d_in[14];
  const float* b_out    = (const float*)d_in[15];
  const int* Dd = (const int*)d_in[16];
  const int* Hh = (const int*)d_in[17];
  const int* Ww = (const int*)d_in[18];
  const int* Tt = (const int*)d_in[19];
  float* out = (float*)d_out;

  ushort* W = (ushort*)d_ws;
  size_t o = 0;
  auto alloc = [&](size_t n) { ushort* p = W + o; o += n; return p; };
  const size_t big = (size_t)L_N * HID_N;   // 8388608 elems
  const size_t LQ = (size_t)L_N * 128;      // 2097152

  ushort* gamma  = alloc(4 * LQ);           // opb aliases here after hband precompute
  ushort* qb     = alloc(LQ);
  ushort* attnout= alloc(4 * LQ);           // kvtmp aliases (early); stays live whole chain
  ushort* tokb   = alloc((size_t)B_N * M_N * HID_N);
  ushort* kbuf   = alloc((size_t)B_N * M_N * 128);
  ushort* vtb    = alloc((size_t)B_N * 128 * M_N);
  ushort* wq_t   = alloc(512 * 128);
  ushort* wtq_t  = alloc(128 * 512);
  ushort* wkv_t  = alloc(256 * 512);
  ushort* wto_t  = alloc(512 * 128);
  ushort* wb_t   = alloc(3 * 512 * 128);
  ushort* wm_t   = alloc(3 * 512 * 512);
  ushort* whv_t  = alloc(2 * 512 * 512);
  float* tbuf    = (float*)alloc(L_N * 2);
  size_t base_u = o;

  // NZ=2 (L3-blocked halves) needs base + 3big(hband) + 3*2big; NZ=1 needs base + 6big
  int NZ = (ws_size >= (base_u + 9 * big) * sizeof(ushort)) ? 2 : 1;
  ushort* hband = alloc(3 * big);                 // [3][L][512], precomputed once
  ushort* modv  = alloc((size_t)NZ * big);
  ushort* hv    = alloc((size_t)NZ * big);
  ushort* tmp   = alloc((size_t)NZ * big);
  ushort* xq = modv;        // alias: xq dead before modv written
  ushort* kvtmp = attnout;  // alias: consumed before attnout written
  float* opb = (float*)gamma;  // gamma dead after hband precompute (9.4 MB <= 16.8 MB)

  const long long BG = (long long)big;
  const long long LQs = (long long)LQ;
  const size_t SLOT = (size_t)4 * B_N * L_N * 3;  // opb slot stride (floats)

  // ---- prep ----
  k_wt_all<<<dim3(1792), 256, 0, stream>>>(w_query, w_to_q, w_to_kv, w_to_out, w_band, w_mod, w_hv,
                                           wq_t, wtq_t, wkv_t, wto_t, wb_t, wm_t, whv_t);
  k_cvt<<<dim3(512), 256, 0, stream>>>(tokens, tokb, B_N * M_N * HID_N / 4);
  k_gamma<<<dim3(L_N / 16, 4), 256, 0, stream>>>(x, gamma);
  k_tpos<<<dim3(L_N / 256), 256, 0, stream>>>(x, Dd, Hh, Ww, Tt, tbuf);

  // ---- pre-pass ----
  k_gemm2<<<dim3(4 * 128), 256, 0, stream>>>(gamma, 0, wq_t, 0, b_query, 0, nullptr, nullptr, 0,
                                             xq, 0, nullptr, nullptr, 0, 512, 128, 1, 4, 128, 1);
  k_gemm2<<<dim3(1 * 128), 256, 0, stream>>>(xq, 0, wtq_t, 0, nullptr, 0, nullptr, nullptr, 0,
                                             qb, 0, nullptr, nullptr, 0, 128, 512, 0, 1, 128, 1);
  k_gemm2<<<dim3(2 * 8), 256, 0, stream>>>(tokb, 0, wkv_t, 0, nullptr, 0, nullptr, nullptr, 0,
                                           kvtmp, 0, nullptr, nullptr, 0, 256, 512, 0, 2, 8, 1);
  k_rearr<<<dim3(1024), 256, 0, stream>>>(kvtmp, kbuf, vtb);
  k_attn_m<<<dim3(L_N / 64, 2, 4), 256, 0, stream>>>(qb, tbuf, kbuf, vtb, attnout);
  // hband[k] = relu(gamma_{1+k} @ wb_k^T + bb_k): one nz=3 launch (gamma dead after this)
  k_gemm2<<<dim3(4 * 128 * 3), 256, 0, stream>>>(gamma + LQ, LQs, wb_t, 65536, b_band, 512,
                                                 nullptr, nullptr, 0, hband, BG,
                                                 nullptr, nullptr, 0, 512, 128, 1, 4, 128, 3);

  // ---- chain, L3-blocked in z-groups of NZ ----
  for (int zoff = 0; zoff < B_N; zoff += NZ) {
    k_gemm2<<<dim3(4 * 128 * NZ), 256, 0, stream>>>(attnout + (size_t)zoff * LQ, LQs, wto_t, 0,
                                                    b_to_out, 0, nullptr, nullptr, 0,
                                                    modv, BG, nullptr, nullptr, 0,
                                                    512, 128, 0, 4, 128, NZ);
    for (int kk = 0; kk < 3; ++kk) {
      if (kk == 0) {
        // hv = relu(hband0 + modv@wm0 + bm0); fused w_out slot0
        k_gemm2<<<dim3(4 * 128 * NZ), 256, 0, stream>>>(modv, BG, wm_t, 0, b_mod, 0, hband,
                                                        nullptr, 0, hv, BG,
                                                        w_out, opb, zoff, 512, 512, 1, 4, 128, NZ);
      } else {
        // tmp = relu(hband_kk + modv@wm_kk + bm_kk) + hv
        k_gemm2<<<dim3(4 * 128 * NZ), 256, 0, stream>>>(modv, BG, wm_t + (size_t)kk * 262144, 0,
                                                        b_mod + kk * 512, 0, hband + (size_t)kk * big,
                                                        hv, BG, tmp, BG,
                                                        nullptr, nullptr, 0, 512, 512, 1, 4, 128, NZ);
        // hv = relu(tmp@whv + bh); fused w_out slot kk
        k_gemm2<<<dim3(4 * 128 * NZ), 256, 0, stream>>>(tmp, BG, whv_t + (size_t)(kk - 1) * 262144, 0,
                                                        b_hv + (kk - 1) * 512, 0, nullptr,
                                                        nullptr, 0, hv, BG,
                                                        w_out + (size_t)kk * 1536, opb + (size_t)kk * SLOT,
                                                        zoff, 512, 512, 1, 4, 128, NZ);
      }
    }
  }
  k_outred<<<dim3((B_N * L_N + 255) / 256), 256, 0, stream>>>(opb, b_out, out);
}

// Round 10
// 392.297 us; speedup vs baseline: 1.3223x; 1.1434x over previous
//
#include <hip/hip_runtime.h>

#define L_N   16384
#define B_N   4
#define M_N   256
#define HID_N 512
#define PI_F  3.14159265358979323846f

typedef short short8 __attribute__((ext_vector_type(8)));
typedef float f32x4 __attribute__((ext_vector_type(4)));

__device__ __forceinline__ ushort f2bf(float f) {
  uint u = __float_as_uint(f);
  uint r = u + 0x7FFF + ((u >> 16) & 1);
  return (ushort)(r >> 16);
}
__device__ __forceinline__ float bf2f(ushort s) {
  return __uint_as_float(((uint)s) << 16);
}
__device__ __forceinline__ void gld_lds16(const void* g, void* s) {
  __builtin_amdgcn_global_load_lds((const __attribute__((address_space(1))) void*)g,
                                   (__attribute__((address_space(3))) void*)s, 16, 0, 0);
}

// ---------- merged weight transpose: fp32 [R][C] -> bf16 [C][R] ----------
__global__ __launch_bounds__(256) void k_wt_all(
    const float* __restrict__ w_query, const float* __restrict__ w_to_q,
    const float* __restrict__ w_to_kv, const float* __restrict__ w_to_out,
    const float* __restrict__ w_band, const float* __restrict__ w_mod,
    const float* __restrict__ w_hv,
    ushort* __restrict__ wq_t, ushort* __restrict__ wtq_t,
    ushort* __restrict__ wkv_t, ushort* __restrict__ wto_t,
    ushort* __restrict__ wb_t, ushort* __restrict__ wm_t, ushort* __restrict__ whv_t) {
  __shared__ float t[32][33];
  int tb = blockIdx.x;
  const float* in; ushort* out; int R, C;
  if (tb < 64)        { in = w_query;  out = wq_t;  R = 128; C = 512; }
  else if (tb < 128)  { tb -= 64;  in = w_to_q;   out = wtq_t; R = 512; C = 128; }
  else if (tb < 256)  { tb -= 128; in = w_to_kv;  out = wkv_t; R = 512; C = 256; }
  else if (tb < 320)  { tb -= 256; in = w_to_out; out = wto_t; R = 128; C = 512; }
  else if (tb < 512)  { tb -= 320; int kk = tb >> 6; tb &= 63;
                        in = w_band + (size_t)kk * 65536; out = wb_t + (size_t)kk * 65536; R = 128; C = 512; }
  else if (tb < 1280) { tb -= 512; int kk = tb >> 8; tb &= 255;
                        in = w_mod + (size_t)kk * 262144; out = wm_t + (size_t)kk * 262144; R = 512; C = 512; }
  else                { tb -= 1280; int kk = tb >> 8; tb &= 255;
                        in = w_hv + (size_t)kk * 262144; out = whv_t + (size_t)kk * 262144; R = 512; C = 512; }
  int nbx = C >> 5;
  int bx = (tb % nbx) * 32, by = (tb / nbx) * 32;
  int tx = threadIdx.x & 31, ty = threadIdx.x >> 5;
#pragma unroll
  for (int j = 0; j < 32; j += 8) t[ty + j][tx] = in[(size_t)(by + ty + j) * C + bx + tx];
  __syncthreads();
#pragma unroll
  for (int j = 0; j < 32; j += 8)
    out[(size_t)(bx + ty + j) * R + by + tx] = f2bf(t[tx][ty + j]);
}

// ---------- fp32 -> bf16 elementwise ----------
__global__ __launch_bounds__(256) void k_cvt(const float* __restrict__ in,
                                             ushort* __restrict__ out, int n4) {
  int i = blockIdx.x * 256 + threadIdx.x;
  if (i >= n4) return;
  float4 v = *(const float4*)&in[(size_t)i * 4];
  ushort* o = &out[(size_t)i * 4];
  o[0] = f2bf(v.x); o[1] = f2bf(v.y); o[2] = f2bf(v.z); o[3] = f2bf(v.w);
}

// ---------- gamma: [4 specs][L][128] bf16 ----------
__global__ __launch_bounds__(256) void k_gamma(const float* __restrict__ x,
                                               ushort* __restrict__ gout) {
  __shared__ float om[16];
  const float lgs[4] = {2.1072099696478683f, 2.1072099696478683f,
                        1.5051499783199058f, 0.9030899869919435f};
  int spec = blockIdx.y;
  float lg = lgs[spec];
  int tid = threadIdx.x;
  if (tid < 16) om[tid] = powf(10.0f, 1.0f + (float)tid * ((lg - 1.0f) * (1.0f / 15.0f)));
  __syncthreads();
  int l0 = blockIdx.x * 16;
  int idx0 = tid * 8;
  int row = idx0 >> 7, f0 = idx0 & 127;
  int c = f0 >> 5;
  float g = x[(size_t)(l0 + row) * 4 + c];
  float base = PI_F * g;
  int w0 = f0 & 31;
  bool is_cos = (w0 >= 16);
  short8 o;
#pragma unroll
  for (int j = 0; j < 8; ++j) {
    int jf = (w0 + j) & 15;
    float arg = base * om[jf];
    float v = is_cos ? __cosf(arg) : __sinf(arg);
    o[j] = (short)f2bf(v);
  }
  *(short8*)&gout[(size_t)spec * L_N * 128 + (size_t)(l0 + row) * 128 + f0] = o;
}

// ---------- t positions ----------
__global__ __launch_bounds__(256) void k_tpos(const float* __restrict__ x,
                                              const int* dD, const int* dH,
                                              const int* dW, const int* dT,
                                              float* __restrict__ tbuf) {
  int l = blockIdx.x * 256 + threadIdx.x;
  float g0 = x[(size_t)l * 4 + 0], g1 = x[(size_t)l * 4 + 1];
  float g2 = x[(size_t)l * 4 + 2], g3 = x[(size_t)l * 4 + 3];
  int Dd = dD[0], Hh = dH[0], Ww = dW[0], Tt = dT[0];
  int zi = (int)(g0 * (float)Dd), yi = (int)(g1 * (float)Hh);
  int xi = (int)(g2 * (float)Ww), ti = (int)(g3 * (float)Tt);
  int idx = ((ti * Dd + zi) * Hh + yi) * Ww + xi;
  tbuf[l] = (float)idx / (float)(Dd * Hh * Ww * Tt);
}

// ---------- generic bf16 MFMA GEMM, 128x128 tile, BK=64, single-buffer LDS ----------
// C may be null (partials-only). opb accumulates (+=); k_mpair initializes it.
__global__ __launch_bounds__(256, 4) void k_gemm2(
    const ushort* __restrict__ A, long long sA,
    const ushort* __restrict__ Wt, long long sWt,
    const float* __restrict__ bias, int sBias,
    const ushort* __restrict__ add1,
    const ushort* add2, long long sAdd2,
    ushort* C, long long sC,
    const float* __restrict__ wout,
    float* __restrict__ opb,
    int zoff,
    int N, int K, int do_relu,
    int nbx, int nby, int nz) {
  __shared__ __align__(16) ushort S[128 * 64 * 2];   // 32 KB: As | Ws
  __shared__ float woutL[384];
  ushort* As = S;
  ushort* Ws = S + 128 * 64;
  int tid = threadIdx.x;
  int lane = tid & 63, wid = tid >> 6;

  int nwg = nbx * nby * nz;
  int gid0 = blockIdx.x;
  int q = nwg >> 3, r = nwg & 7;
  int xcd = gid0 & 7, rank = gid0 >> 3;
  int sid = (xcd < r) ? (xcd * (q + 1) + rank) : (r * (q + 1) + (xcd - r) * q + rank);
  int z = sid / (nbx * nby);
  int rem = sid - z * (nbx * nby);
  int n0 = (rem % nbx) * 128, r0 = (rem / nbx) * 128;

  A += (size_t)z * sA;
  ushort* Cp = C ? C + (size_t)z * sC : nullptr;
  const ushort* Wtp = Wt + (size_t)z * sWt;
  const float* biasp = bias ? bias + (size_t)z * sBias : nullptr;
  const ushort* a2p = add2 ? add2 + (size_t)z * sAdd2 : nullptr;
  int wr = wid >> 1, wc = wid & 1;
  int ksm = K >> 6;

  f32x4 acc[4][4];
#pragma unroll
  for (int i = 0; i < 4; ++i)
#pragma unroll
    for (int j = 0; j < 4; ++j) acc[i][j] = (f32x4)0.0f;

  for (int t = 0; t < ksm; ++t) {
#pragma unroll
    for (int j = 0; j < 4; ++j) {
      int sig = j * 256 + wid * 64 + lane;
      int rr = sig >> 3, ph = sig & 7, sl = ph ^ (rr & 7);
      gld_lds16(&A[(size_t)(r0 + rr) * K + t * 64 + sl * 8], &As[(size_t)(j * 256 + wid * 64) * 8]);
      gld_lds16(&Wtp[(size_t)(n0 + rr) * K + t * 64 + sl * 8], &Ws[(size_t)(j * 256 + wid * 64) * 8]);
    }
    __syncthreads();
#pragma unroll
    for (int ks = 0; ks < 2; ++ks) {
      short8 af[4], bg[4];
#pragma unroll
      for (int fm = 0; fm < 4; ++fm) {
        int row = wr * 64 + fm * 16 + (lane & 15);
        af[fm] = *(const short8*)&As[row * 64 + (((ks * 4 + (lane >> 4)) ^ (row & 7)) * 8)];
      }
#pragma unroll
      for (int fn = 0; fn < 4; ++fn) {
        int nl = wc * 64 + fn * 16 + (lane & 15);
        bg[fn] = *(const short8*)&Ws[nl * 64 + (((ks * 4 + (lane >> 4)) ^ (nl & 7)) * 8)];
      }
#pragma unroll
      for (int fm = 0; fm < 4; ++fm)
#pragma unroll
        for (int fn = 0; fn < 4; ++fn)
          acc[fm][fn] = __builtin_amdgcn_mfma_f32_16x16x32_bf16(af[fm], bg[fn], acc[fm][fn], 0, 0, 0);
    }
    __syncthreads();
  }

  if (wout && tid < 128) {
    woutL[tid * 3 + 0] = wout[(size_t)(n0 + tid) * 3 + 0];
    woutL[tid * 3 + 1] = wout[(size_t)(n0 + tid) * 3 + 1];
    woutL[tid * 3 + 2] = wout[(size_t)(n0 + tid) * 3 + 2];
  }

  float* Ls = (float*)S;   // [32][132] f32
  int row = tid >> 3;
  int c0 = (tid & 7) * 16;
#pragma unroll
  for (int fm = 0; fm < 4; ++fm) {
    if (fm) __syncthreads();
#pragma unroll
    for (int fn = 0; fn < 4; ++fn)
#pragma unroll
      for (int reg = 0; reg < 4; ++reg) {
        int lr = wr * 16 + (lane >> 4) * 4 + reg;
        int lc = wc * 64 + fn * 16 + (lane & 15);
        Ls[lr * 132 + lc] = acc[fm][fn][reg];
      }
    __syncthreads();
    int gr = r0 + (row >> 4) * 64 + fm * 16 + (row & 15);
    float so0 = 0.0f, so1 = 0.0f, so2 = 0.0f;
#pragma unroll
    for (int hh = 0; hh < 2; ++hh) {
      int cc = c0 + hh * 8;
      float v[8];
#pragma unroll
      for (int j = 0; j < 8; ++j) v[j] = Ls[row * 132 + cc + j];
      if (biasp) {
#pragma unroll
        for (int j = 0; j < 8; ++j) v[j] += biasp[n0 + cc + j];
      }
      if (add1) {
        short8 a1 = *(const short8*)&add1[(size_t)gr * N + n0 + cc];
#pragma unroll
        for (int j = 0; j < 8; ++j) v[j] += bf2f((ushort)a1[j]);
      }
      if (do_relu) {
#pragma unroll
        for (int j = 0; j < 8; ++j) v[j] = fmaxf(v[j], 0.0f);
      }
      if (a2p) {
        short8 a2 = *(const short8*)&a2p[(size_t)gr * N + n0 + cc];
#pragma unroll
        for (int j = 0; j < 8; ++j) v[j] += bf2f((ushort)a2[j]);
      }
      if (wout) {
#pragma unroll
        for (int j = 0; j < 8; ++j) {
          so0 = fmaf(v[j], woutL[(cc + j) * 3 + 0], so0);
          so1 = fmaf(v[j], woutL[(cc + j) * 3 + 1], so1);
          so2 = fmaf(v[j], woutL[(cc + j) * 3 + 2], so2);
        }
      }
      if (Cp) {
        short8 ov;
#pragma unroll
        for (int j = 0; j < 8; ++j) ov[j] = (short)f2bf(v[j]);
        *(short8*)&Cp[(size_t)gr * N + n0 + cc] = ov;
      }
    }
    if (wout) {
      so0 += __shfl_down(so0, 4); so1 += __shfl_down(so1, 4); so2 += __shfl_down(so2, 4);
      so0 += __shfl_down(so0, 2); so1 += __shfl_down(so1, 2); so2 += __shfl_down(so2, 2);
      so0 += __shfl_down(so0, 1); so1 += __shfl_down(so1, 1); so2 += __shfl_down(so2, 1);
      if ((tid & 7) == 0) {
        int bx = n0 >> 7;
        size_t oi = (((size_t)bx * 4 + (zoff + z)) * L_N + gr) * 3;
        opb[oi + 0] += so0; opb[oi + 1] += so1; opb[oi + 2] += so2;
      }
    }
  }
}

// ---------- paired m-GEMM: s1 = m0 + m1, two accumulators sharing A-stage ----------
// m_k = relu(hband_k + modv@wm_k^T + bm_k); also writes (init) opb with m0@wout0.
__global__ __launch_bounds__(256, 2) void k_mpair(
    const ushort* __restrict__ modv,
    const ushort* __restrict__ wm_t,     // [wm0 | wm1] each [512][512]
    const float* __restrict__ b_mod,     // [bm0 | bm1]
    const ushort* __restrict__ hband,    // [hb0 | hb1] each [L][512]
    const float* __restrict__ wout,      // w_out slot0 [512][3]
    float* __restrict__ opb, int zoff,
    ushort* __restrict__ s1,
    int nbx, int nby, int nz) {
  __shared__ __align__(16) ushort S[3 * 128 * 64];   // 48 KB: As | W0 | W1
  __shared__ float woutL[384];
  const size_t big = (size_t)L_N * HID_N;
  ushort* As = S;
  ushort* W0 = S + 128 * 64;
  ushort* W1 = S + 2 * 128 * 64;
  int tid = threadIdx.x;
  int lane = tid & 63, wid = tid >> 6;

  int nwg = nbx * nby * nz;
  int gid0 = blockIdx.x;
  int q = nwg >> 3, r = nwg & 7;
  int xcd = gid0 & 7, rank = gid0 >> 3;
  int sid = (xcd < r) ? (xcd * (q + 1) + rank) : (r * (q + 1) + (xcd - r) * q + rank);
  int z = sid / (nbx * nby);
  int rem = sid - z * (nbx * nby);
  int n0 = (rem % nbx) * 128, r0 = (rem / nbx) * 128;

  const ushort* A = modv + (size_t)z * big;
  ushort* Cp = s1 + (size_t)z * big;
  int wr = wid >> 1, wc = wid & 1;

  f32x4 acc0[4][4], acc1[4][4];
#pragma unroll
  for (int i = 0; i < 4; ++i)
#pragma unroll
    for (int j = 0; j < 4; ++j) { acc0[i][j] = (f32x4)0.0f; acc1[i][j] = (f32x4)0.0f; }

  for (int t = 0; t < 8; ++t) {
#pragma unroll
    for (int j = 0; j < 4; ++j) {
      int sig = j * 256 + wid * 64 + lane;
      int rr = sig >> 3, ph = sig & 7, sl = ph ^ (rr & 7);
      gld_lds16(&A[(size_t)(r0 + rr) * 512 + t * 64 + sl * 8], &As[(size_t)sig * 8]);
      gld_lds16(&wm_t[(size_t)(n0 + rr) * 512 + t * 64 + sl * 8], &W0[(size_t)sig * 8]);
      gld_lds16(&wm_t[262144 + (size_t)(n0 + rr) * 512 + t * 64 + sl * 8], &W1[(size_t)sig * 8]);
    }
    __syncthreads();
#pragma unroll
    for (int ks = 0; ks < 2; ++ks) {
      short8 af[4], bg0[4], bg1[4];
#pragma unroll
      for (int fm = 0; fm < 4; ++fm) {
        int rrow = wr * 64 + fm * 16 + (lane & 15);
        af[fm] = *(const short8*)&As[rrow * 64 + (((ks * 4 + (lane >> 4)) ^ (rrow & 7)) * 8)];
      }
#pragma unroll
      for (int fn = 0; fn < 4; ++fn) {
        int nl = wc * 64 + fn * 16 + (lane & 15);
        int off = nl * 64 + (((ks * 4 + (lane >> 4)) ^ (nl & 7)) * 8);
        bg0[fn] = *(const short8*)&W0[off];
        bg1[fn] = *(const short8*)&W1[off];
      }
#pragma unroll
      for (int fm = 0; fm < 4; ++fm)
#pragma unroll
        for (int fn = 0; fn < 4; ++fn) {
          acc0[fm][fn] = __builtin_amdgcn_mfma_f32_16x16x32_bf16(af[fm], bg0[fn], acc0[fm][fn], 0, 0, 0);
          acc1[fm][fn] = __builtin_amdgcn_mfma_f32_16x16x32_bf16(af[fm], bg1[fn], acc1[fm][fn], 0, 0, 0);
        }
    }
    __syncthreads();
  }

  if (tid < 128) {
    woutL[tid * 3 + 0] = wout[(size_t)(n0 + tid) * 3 + 0];
    woutL[tid * 3 + 1] = wout[(size_t)(n0 + tid) * 3 + 1];
    woutL[tid * 3 + 2] = wout[(size_t)(n0 + tid) * 3 + 2];
  }

  float* Ls0 = (float*)S;               // [32][132]
  float* Ls1 = (float*)S + 32 * 132;    // [32][132]
  int row = tid >> 3;
  int c0 = (tid & 7) * 16;
#pragma unroll
  for (int fm = 0; fm < 4; ++fm) {
    if (fm) __syncthreads();
#pragma unroll
    for (int fn = 0; fn < 4; ++fn)
#pragma unroll
      for (int reg = 0; reg < 4; ++reg) {
        int lr = wr * 16 + (lane >> 4) * 4 + reg;
        int lc = wc * 64 + fn * 16 + (lane & 15);
        Ls0[lr * 132 + lc] = acc0[fm][fn][reg];
        Ls1[lr * 132 + lc] = acc1[fm][fn][reg];
      }
    __syncthreads();
    int gr = r0 + (row >> 4) * 64 + fm * 16 + (row & 15);
    float so0 = 0.0f, so1 = 0.0f, so2 = 0.0f;
#pragma unroll
    for (int hh = 0; hh < 2; ++hh) {
      int cc = c0 + hh * 8;
      short8 h0 = *(const short8*)&hband[(size_t)gr * 512 + n0 + cc];
      short8 h1 = *(const short8*)&hband[big + (size_t)gr * 512 + n0 + cc];
      float v0[8], v1[8];
#pragma unroll
      for (int j = 0; j < 8; ++j) {
        v0[j] = fmaxf(Ls0[row * 132 + cc + j] + b_mod[n0 + cc + j] + bf2f((ushort)h0[j]), 0.0f);
        v1[j] = fmaxf(Ls1[row * 132 + cc + j] + b_mod[512 + n0 + cc + j] + bf2f((ushort)h1[j]), 0.0f);
        so0 = fmaf(v0[j], woutL[(cc + j) * 3 + 0], so0);
        so1 = fmaf(v0[j], woutL[(cc + j) * 3 + 1], so1);
        so2 = fmaf(v0[j], woutL[(cc + j) * 3 + 2], so2);
      }
      short8 ov;
#pragma unroll
      for (int j = 0; j < 8; ++j) ov[j] = (short)f2bf(v0[j] + v1[j]);
      *(short8*)&Cp[(size_t)gr * 512 + n0 + cc] = ov;
    }
    so0 += __shfl_down(so0, 4); so1 += __shfl_down(so1, 4); so2 += __shfl_down(so2, 4);
    so0 += __shfl_down(so0, 2); so1 += __shfl_down(so1, 2); so2 += __shfl_down(so2, 2);
    so0 += __shfl_down(so0, 1); so1 += __shfl_down(so1, 1); so2 += __shfl_down(so2, 1);
    if ((tid & 7) == 0) {
      int bx = n0 >> 7;
      size_t oi = (((size_t)bx * 4 + (zoff + z)) * L_N + gr) * 3;
      opb[oi + 0] = so0; opb[oi + 1] = so1; opb[oi + 2] = so2;   // INIT
    }
  }
}

// ---------- reduce out partials: out[z][l] = sum over 4 bx + biases ----------
__global__ __launch_bounds__(256) void k_outred(const float* __restrict__ opb,
                                                const float* __restrict__ b_out,
                                                float* __restrict__ out) {
  int i = blockIdx.x * 256 + threadIdx.x;  // z*L + l
  if (i >= B_N * L_N) return;
  float a0 = b_out[0] + b_out[3] + b_out[6];
  float a1 = b_out[1] + b_out[4] + b_out[7];
  float a2 = b_out[2] + b_out[5] + b_out[8];
#pragma unroll
  for (int bx = 0; bx < 4; ++bx) {
    const float* p = opb + ((size_t)bx * 4 * L_N + i) * 3;
    a0 += p[0]; a1 += p[1]; a2 += p[2];
  }
  out[(size_t)i * 3 + 0] = a0;
  out[(size_t)i * 3 + 1] = a1;
  out[(size_t)i * 3 + 2] = a2;
}

// ---------- kv rearrange ----------
__global__ __launch_bounds__(256) void k_rearr(const ushort* __restrict__ kvtmp,
                                               ushort* __restrict__ kbuf,
                                               ushort* __restrict__ vtb) {
  int i = blockIdx.x * 256 + threadIdx.x;
  int col = i & 255, row = i >> 8;
  int b = row >> 8, m = row & 255;
  ushort v = kvtmp[i];
  if (col < 128)
    kbuf[((size_t)b * 256 + m) * 128 + col] = v;
  else
    vtb[(size_t)b * 128 * 256 + (size_t)(col - 128) * 256 + m] = v;
}

// ---------- MFMA attention per (b, head) ----------
__global__ __launch_bounds__(256) void k_attn_m(const ushort* __restrict__ qbuf,
                                                const float* __restrict__ tbuf,
                                                const ushort* __restrict__ kbuf,
                                                const ushort* __restrict__ vtb,
                                                ushort* __restrict__ attn) {
  __shared__ __align__(16) ushort Kt[256 * 64];
  __shared__ __align__(16) ushort Vt[64 * 256];
  __shared__ __align__(16) ushort Qs[64 * 64];
  __shared__ __align__(16) ushort Pw[4][16 * 40];
  __shared__ float ts[64];
  int tid = threadIdx.x;
  int lane = tid & 63, wid = tid >> 6;
  int l0 = blockIdx.x * 64;
  int h = blockIdx.y;
  int z = blockIdx.z;
  const ushort* kbuf_b = kbuf + (size_t)z * M_N * 128;
  const ushort* vtb_b = vtb + (size_t)z * 128 * M_N;
  ushort* attn_b = attn + (size_t)z * L_N * 128;
#pragma unroll
  for (int j = 0; j < 8; ++j) {
    int sig = j * 256 + wid * 64 + lane;
    int m = sig >> 3, ph = sig & 7, sl = ph ^ (m & 7);
    gld_lds16(&kbuf_b[(size_t)m * 128 + h * 64 + sl * 8], &Kt[(size_t)(j * 256 + wid * 64) * 8]);
  }
#pragma unroll
  for (int j = 0; j < 8; ++j) {
    int sig = j * 256 + wid * 64 + lane;
    int d = sig >> 5, ph = sig & 31, sl = ph ^ ((d & 7) << 2);
    gld_lds16(&vtb_b[(size_t)(h * 64 + d) * 256 + sl * 8], &Vt[(size_t)(j * 256 + wid * 64) * 8]);
  }
#pragma unroll
  for (int j = 0; j < 2; ++j) {
    int sig = j * 256 + wid * 64 + lane;
    int qq = sig >> 3, ph = sig & 7, sl = ph ^ (qq & 7);
    gld_lds16(&qbuf[(size_t)(l0 + qq) * 128 + h * 64 + sl * 8], &Qs[(size_t)(j * 256 + wid * 64) * 8]);
  }
  if (tid < 64) ts[tid] = tbuf[l0 + tid];
  __syncthreads();

  f32x4 s_acc[16];
#pragma unroll
  for (int fn = 0; fn < 16; ++fn) s_acc[fn] = (f32x4)0.0f;
#pragma unroll
  for (int ks = 0; ks < 2; ++ks) {
    int qrow = wid * 16 + (lane & 15);
    short8 aq = *(const short8*)&Qs[qrow * 64 + (((ks * 4 + (lane >> 4)) ^ (qrow & 7)) * 8)];
#pragma unroll
    for (int fn = 0; fn < 16; ++fn) {
      int m = fn * 16 + (lane & 15);
      short8 bk = *(const short8*)&Kt[m * 64 + (((ks * 4 + (lane >> 4)) ^ (m & 7)) * 8)];
      s_acc[fn] = __builtin_amdgcn_mfma_f32_16x16x32_bf16(aq, bk, s_acc[fn], 0, 0, 0);
    }
  }
  float mx[4] = {-1e30f, -1e30f, -1e30f, -1e30f};
#pragma unroll
  for (int fn = 0; fn < 16; ++fn) {
#pragma unroll
    for (int reg = 0; reg < 4; ++reg) {
      int ql = wid * 16 + (lane >> 4) * 4 + reg;
      int m = fn * 16 + (lane & 15);
      float mp = ((float)m + 0.5f) * (1.0f / 256.0f);
      float d = ts[ql] - mp;
      float v = s_acc[fn][reg] * 0.125f - 10.0f * d * d;
      s_acc[fn][reg] = v;
      mx[reg] = fmaxf(mx[reg], v);
    }
  }
#pragma unroll
  for (int reg = 0; reg < 4; ++reg) {
    mx[reg] = fmaxf(mx[reg], __shfl_xor(mx[reg], 1));
    mx[reg] = fmaxf(mx[reg], __shfl_xor(mx[reg], 2));
    mx[reg] = fmaxf(mx[reg], __shfl_xor(mx[reg], 4));
    mx[reg] = fmaxf(mx[reg], __shfl_xor(mx[reg], 8));
  }
  float sm[4] = {0.0f, 0.0f, 0.0f, 0.0f};
#pragma unroll
  for (int fn = 0; fn < 16; ++fn) {
#pragma unroll
    for (int reg = 0; reg < 4; ++reg) {
      float e = __expf(s_acc[fn][reg] - mx[reg]);
      s_acc[fn][reg] = e;
      sm[reg] += e;
    }
  }
#pragma unroll
  for (int reg = 0; reg < 4; ++reg) {
    sm[reg] += __shfl_xor(sm[reg], 1);
    sm[reg] += __shfl_xor(sm[reg], 2);
    sm[reg] += __shfl_xor(sm[reg], 4);
    sm[reg] += __shfl_xor(sm[reg], 8);
  }
  float inv[4];
#pragma unroll
  for (int reg = 0; reg < 4; ++reg) inv[reg] = 1.0f / sm[reg];

  f32x4 o_acc[4];
#pragma unroll
  for (int fn = 0; fn < 4; ++fn) o_acc[fn] = (f32x4)0.0f;
  for (int kk = 0; kk < 8; ++kk) {
#pragma unroll
    for (int fp = 0; fp < 2; ++fp) {
      int fn = kk * 2 + fp;
#pragma unroll
      for (int reg = 0; reg < 4; ++reg) {
        int ql16 = (lane >> 4) * 4 + reg;
        int mc = fp * 16 + (lane & 15);
        Pw[wid][ql16 * 40 + mc] = f2bf(s_acc[fn][reg] * inv[reg]);
      }
    }
    asm volatile("s_waitcnt lgkmcnt(0)" ::: "memory");
    __builtin_amdgcn_sched_barrier(0);
    short8 pa = *(const short8*)&Pw[wid][(lane & 15) * 40 + (lane >> 4) * 8];
#pragma unroll
    for (int fn = 0; fn < 4; ++fn) {
      int dr = fn * 16 + (lane & 15);
      short8 vb = *(const short8*)&Vt[dr * 256 + (((kk * 4 + (lane >> 4)) ^ ((dr & 7) << 2)) * 8)];
      o_acc[fn] = __builtin_amdgcn_mfma_f32_16x16x32_bf16(pa, vb, o_acc[fn], 0, 0, 0);
    }
    asm volatile("s_waitcnt lgkmcnt(0)" ::: "memory");
    __builtin_amdgcn_sched_barrier(0);
  }
#pragma unroll
  for (int fn = 0; fn < 4; ++fn)
#pragma unroll
    for (int reg = 0; reg < 4; ++reg) {
      int ql = l0 + wid * 16 + (lane >> 4) * 4 + reg;
      attn_b[(size_t)ql * 128 + h * 64 + fn * 16 + (lane & 15)] = f2bf(o_acc[fn][reg]);
    }
}

extern "C" void kernel_launch(void* const* d_in, const int* in_sizes, int n_in,
                              void* d_out, int out_size, void* d_ws, size_t ws_size,
                              hipStream_t stream) {
  const float* x        = (const float*)d_in[0];
  const float* tokens   = (const float*)d_in[1];
  const float* w_query  = (const float*)d_in[2];
  const float* b_query  = (const float*)d_in[3];
  const float* w_to_q   = (const float*)d_in[4];
  const float* w_to_kv  = (const float*)d_in[5];
  const float* w_to_out = (const float*)d_in[6];
  const float* b_to_out = (const float*)d_in[7];
  const float* w_band   = (const float*)d_in[8];
  const float* b_band   = (const float*)d_in[9];
  const float* w_mod    = (const float*)d_in[10];
  const float* b_mod    = (const float*)d_in[11];
  const float* w_hv     = (const float*)d_in[12];
  const float* b_hv     = (const float*)d_in[13];
  const float* w_out    = (const float*)d_in[14];
  const float* b_out    = (const float*)d_in[15];
  const int* Dd = (const int*)d_in[16];
  const int* Hh = (const int*)d_in[17];
  const int* Ww = (const int*)d_in[18];
  const int* Tt = (const int*)d_in[19];
  float* out = (float*)d_out;

  ushort* W = (ushort*)d_ws;
  size_t o = 0;
  auto alloc = [&](size_t n) { ushort* p = W + o; o += n; return p; };
  const size_t big = (size_t)L_N * HID_N;   // 8388608 elems = 16.8 MB
  const size_t LQ = (size_t)L_N * 128;

  // misc (no gamma/attnout here)
  ushort* qb     = alloc(LQ);               // opb aliases after attn
  ushort* tokb   = alloc((size_t)B_N * M_N * HID_N);
  ushort* kbuf   = alloc((size_t)B_N * M_N * 128);
  ushort* vtb    = alloc((size_t)B_N * 128 * M_N);
  ushort* wq_t   = alloc(512 * 128);
  ushort* wtq_t  = alloc(128 * 512);
  ushort* wkv_t  = alloc(256 * 512);
  ushort* wto_t  = alloc(512 * 128);
  ushort* wb_t   = alloc(3 * 512 * 128);
  ushort* wm_t   = alloc(3 * 512 * 512);
  ushort* whv_t  = alloc(2 * 512 * 512);
  float* tbuf    = (float*)alloc(L_N * 2);
  size_t base_u = o;

  int NZ;
  if (ws_size >= (base_u + 15 * big) * sizeof(ushort)) NZ = 4;
  else if (ws_size >= (base_u + 10 * big) * sizeof(ushort)) NZ = 2;
  else NZ = 1;

  ushort *gammaR, *attnout, *s1, *hband, *modv, *hv1;
  if (NZ == 4) {
    gammaR  = alloc(4 * big);   // gamma (1 big) then hv1 region (4 bigs)
    attnout = alloc(4 * big);   // attnout (1 big) then s1 region (4 bigs)
    hband   = alloc(3 * big);
    modv    = alloc(4 * big);
    hv1 = gammaR;
    s1  = attnout;
  } else {
    gammaR  = alloc((size_t)(NZ > 1 ? NZ : 1) * big);  // gamma + hv1 share
    attnout = alloc(big);
    s1      = alloc((size_t)NZ * big);
    hband   = alloc(3 * big);
    modv    = alloc((size_t)NZ * big);
    hv1 = gammaR;
  }
  ushort* xq = modv;          // alias: xq dead before modv written
  ushort* kvtmp = attnout;    // alias: consumed before attnout written
  float* opb = (float*)qb;    // qb dead after attn; opb = 4bx*4z*L*3 f32 = 3.1 MB <= 4.2 MB

  const long long BG = (long long)big;
  const long long LQs = (long long)LQ;

  // ---- prep ----
  k_wt_all<<<dim3(1792), 256, 0, stream>>>(w_query, w_to_q, w_to_kv, w_to_out, w_band, w_mod, w_hv,
                                           wq_t, wtq_t, wkv_t, wto_t, wb_t, wm_t, whv_t);
  k_cvt<<<dim3(512), 256, 0, stream>>>(tokens, tokb, B_N * M_N * HID_N / 4);
  k_gamma<<<dim3(L_N / 16, 4), 256, 0, stream>>>(x, gammaR);
  k_tpos<<<dim3(L_N / 256), 256, 0, stream>>>(x, Dd, Hh, Ww, Tt, tbuf);

  // ---- pre-pass ----
  k_gemm2<<<dim3(4 * 128), 256, 0, stream>>>(gammaR, 0, wq_t, 0, b_query, 0, nullptr, nullptr, 0,
                                             xq, 0, nullptr, nullptr, 0, 512, 128, 1, 4, 128, 1);
  k_gemm2<<<dim3(1 * 128), 256, 0, stream>>>(xq, 0, wtq_t, 0, nullptr, 0, nullptr, nullptr, 0,
                                             qb, 0, nullptr, nullptr, 0, 128, 512, 0, 1, 128, 1);
  k_gemm2<<<dim3(2 * 8), 256, 0, stream>>>(tokb, 0, wkv_t, 0, nullptr, 0, nullptr, nullptr, 0,
                                           kvtmp, 0, nullptr, nullptr, 0, 256, 512, 0, 2, 8, 1);
  k_rearr<<<dim3(1024), 256, 0, stream>>>(kvtmp, kbuf, vtb);
  k_attn_m<<<dim3(L_N / 64, 2, 4), 256, 0, stream>>>(qb, tbuf, kbuf, vtb, attnout);
  // hband[k] = relu(gamma_{1+k} @ wb_k^T + bb_k): one nz=3 launch; gamma dead after
  k_gemm2<<<dim3(4 * 128 * 3), 256, 0, stream>>>(gammaR + LQ, LQs, wb_t, 65536, b_band, 512,
                                                 nullptr, nullptr, 0, hband, BG,
                                                 nullptr, nullptr, 0, 512, 128, 1, 4, 128, 3);

  // ---- chain ----
  for (int zoff = 0; zoff < B_N; zoff += NZ) {
    // modv = attnout @ wto^T + b_to_out
    k_gemm2<<<dim3(4 * 128 * NZ), 256, 0, stream>>>(attnout + (size_t)zoff * LQ, LQs, wto_t, 0,
                                                    b_to_out, 0, nullptr, nullptr, 0,
                                                    modv, BG, nullptr, nullptr, 0,
                                                    512, 128, 0, 4, 128, NZ);
    // s1 = m0 + m1 (paired); opb init with m0@wout0
    k_mpair<<<dim3(4 * 128 * NZ), 256, 0, stream>>>(modv, wm_t, b_mod, hband, w_out,
                                                    opb, zoff, s1, 4, 128, NZ);
    // hv1 = relu(s1@whv0 + bh0); opb += hv1@wout1
    k_gemm2<<<dim3(4 * 128 * NZ), 256, 0, stream>>>(s1, BG, whv_t, 0, b_hv, 0, nullptr, nullptr, 0,
                                                    hv1, BG, w_out + 1536, opb, zoff,
                                                    512, 512, 1, 4, 128, NZ);
    // s2 = relu(hband2 + modv@wm2 + bm2) + hv1   (writes over s1)
    k_gemm2<<<dim3(4 * 128 * NZ), 256, 0, stream>>>(modv, BG, wm_t + 2 * 262144, 0, b_mod + 1024, 0,
                                                    hband + 2 * big, hv1, BG,
                                                    s1, BG, nullptr, nullptr, 0,
                                                    512, 512, 1, 4, 128, NZ);
    // hv2 partials only: opb += relu(s2@whv1 + bh1)@wout2 (no C write)
    k_gemm2<<<dim3(4 * 128 * NZ), 256, 0, stream>>>(s1, BG, whv_t + 262144, 0, b_hv + 512, 0,
                                                    nullptr, nullptr, 0, nullptr, 0,
                                                    w_out + 3072, opb, zoff,
                                                    512, 512, 1, 4, 128, NZ);
  }
  k_outred<<<dim3((B_N * L_N + 255) / 256), 256, 0, stream>>>(opb, b_out, out);
}